// Round 4
// baseline (184.739 us; speedup 1.0000x reference)
//
#include <hip/hip_runtime.h>
#include <hip/hip_bf16.h>

// MultiHeadAttention B=4,S=4096,D=64,H=4,HD=16 on gfx950.
// softmax over QUERY axis => w[s,t] = E[s,t]/colsum[t], attended = E @ (V/colsum).
// Two MFMA passes recompute E (raw v_exp_f32).  Scores via 32x32x16 bf16 MFMA
// (K=16=HD exact).  PV consumes E directly as the B-operand; the implied k->t
// permutation is absorbed by pre-permuting v' in GLOBAL memory.
// R13: fuse colsum+vprep into k_csvp.  Each wave streams ALL 4096 s (128
// iters, 4-deep NAMED-reg rolling prefetch, outer loop kept rolled for
// I-cache), so the block owns the finished colsum for its 128 t and emits
// the swizzled/packed v' half-chunk directly from an LDS-staged v tile.
// Deletes k_vprep + csp round-trip + one launch.  k_attn unchanged (lb(256,4)
// + rolling kf prefetch + global_load_lds v' DMA).

#define BB 4
#define SS 4096
#define DD 64
#define HH 4
#define HDD 16

typedef unsigned int u32;
typedef unsigned short u16;
typedef __attribute__((ext_vector_type(8))) short bfrag;     // 8 bf16
typedef __attribute__((ext_vector_type(4))) float floatx4;
typedef __attribute__((ext_vector_type(16))) float floatx16;
typedef __attribute__((ext_vector_type(2))) u32 u32x2;
typedef __attribute__((ext_vector_type(4))) u32 u32x4;

#define LOG2E 1.4426950408889634074f
#define QSCALE (LOG2E * 0.25f)

__device__ __forceinline__ float fexp2(float x) {   // raw v_exp_f32
#if __has_builtin(__builtin_amdgcn_exp2f)
  return __builtin_amdgcn_exp2f(x);
#else
  float r; asm("v_exp_f32 %0, %1" : "=v"(r) : "v"(x)); return r;
#endif
}
__device__ __forceinline__ float frcp(float x) {    // raw v_rcp_f32
#if __has_builtin(__builtin_amdgcn_rcpf)
  return __builtin_amdgcn_rcpf(x);
#else
  float r; asm("v_rcp_f32 %0, %1" : "=v"(r) : "v"(x)); return r;
#endif
}

__device__ __forceinline__ u16 f2bf(float f) {      // RNE
  u32 u = __builtin_bit_cast(u32, f);
  return (u16)((u + 0x7FFFu + ((u >> 16) & 1u)) >> 16);
}
// pack two fp32 -> bf16x2 by truncation (E>=0), single v_perm_b32
__device__ __forceinline__ u32 pack_bf(float lo, float hi) {
#if __has_builtin(__builtin_amdgcn_perm)
  return __builtin_amdgcn_perm(__builtin_bit_cast(u32, hi),
                               __builtin_bit_cast(u32, lo), 0x07060302u);
#else
  u32 a = __builtin_bit_cast(u32, lo);
  u32 b = __builtin_bit_cast(u32, hi);
  return (a >> 16) | (b & 0xFFFF0000u);
#endif
}

// global -> LDS DMA, 16B per lane.  LDS dest = wave-uniform base + lane*16.
__device__ __forceinline__ void gload_lds16(const u16* g, u16* l) {
  __builtin_amdgcn_global_load_lds(
      (const __attribute__((address_space(1))) void*)(g),
      (__attribute__((address_space(3))) void*)(l), 16, 0, 0);
}

// fragment column c (0..255 within a 256-t chunk) -> t within chunk.
__device__ __forceinline__ int tmap(int c) {
  int c5 = c & 31;
  return (c & ~31) + (c5 & 3) + ((c5 >> 2) & 1) * 8 + ((c5 >> 3) & 1) * 16
       + ((c5 >> 4) & 1) * 4;
}

// ---------------------------------------------------------------------------
// K1: projections. x[B,S,64] -> q bf16 (scaled, bias folded), k bf16, v fp32;
// layout [B,H,S,16].
// ---------------------------------------------------------------------------
__global__ __launch_bounds__(256) void k_proj(
    const float* __restrict__ x,
    const float* __restrict__ Wq, const float* __restrict__ bq,
    const float* __restrict__ Wk, const float* __restrict__ bk,
    const float* __restrict__ Wv, const float* __restrict__ bv,
    u16* __restrict__ qb, u16* __restrict__ kb, float* __restrict__ vf)
{
  __shared__ float xs[16 * 64];
  const int tid = threadIdx.x;
  const int blk = blockIdx.x;            // B*S/16 = 1024
  const int b   = blk >> 8;
  const int s0  = (blk & 255) << 4;
  ((float4*)xs)[tid] = ((const float4*)(x + ((size_t)b * SS + s0) * DD))[tid];
  __syncthreads();

  const int col = tid & 63, h = col >> 4, e = col & 15;
  const int rg  = tid >> 6;              // wave id; 4 rows each
  float aq[4] = {0,0,0,0}, ak[4] = {0,0,0,0}, av[4] = {0,0,0,0};
  const int wofs = h * (DD * HDD) + e;
#pragma unroll 4
  for (int d = 0; d < DD; ++d) {
    float wq = Wq[wofs + d * HDD];
    float wk = Wk[wofs + d * HDD];
    float wv = Wv[wofs + d * HDD];
    const float* xr = xs + (rg * 4) * 64 + d;
#pragma unroll
    for (int r = 0; r < 4; ++r) {
      float xv = xr[r * 64];
      aq[r] += xv * wq; ak[r] += xv * wk; av[r] += xv * wv;
    }
  }
  const float bqv = bq[col], bkv = bk[col], bvv = bv[col];
  size_t base = ((size_t)(b * HH + h) * SS + (s0 + rg * 4)) * HDD + e;
#pragma unroll
  for (int r = 0; r < 4; ++r) {
    qb[base + r * HDD] = f2bf((aq[r] + bqv) * QSCALE);
    kb[base + r * HDD] = f2bf(ak[r] + bkv);
    vf[base + r * HDD] = av[r] + bvv;
  }
}

// ---------------------------------------------------------------------------
// K2: fused colsum + v'-prep.  Each wave streams ALL 4096 s for its 32 t
// (mfma(Q,K): D[m=s][n=t], col=lane&31 -> t; s-reduction IN-LANE + one
// shfl_xor(32)).  4-deep rolling prefetch in NAMED regs; outer loop rolled
// (I-cache).  Block then holds finished colsum for its 128 t -> rcp to LDS,
// gather from LDS-staged v tile, write packed/swizzled v' half-chunk with
// coalesced 16B stores.  vp[bh][chunk256][flat4096], flat = e*256 +
// (cc^(e&7))*8 + j, source col c = cc*8+j, t = tmap(c).
// ---------------------------------------------------------------------------
__global__ __launch_bounds__(256, 4) void k_csvp(
    const u16* __restrict__ qb, const u16* __restrict__ kb,
    const float* __restrict__ vf, u16* __restrict__ vp)
{
  __shared__ float vstage[128 * 16];     // [tl][e], 8 KB
  __shared__ float rcl[128];
  const int tid = threadIdx.x;
  const int lane = tid & 63, w = tid >> 6;
  const int l31 = lane & 31, hl = lane >> 5;
  const int bx = blockIdx.x;             // 32 t-blocks of 128
  const int bh = blockIdx.y;             // 16
  const int t0 = bx * 128 + w * 32;
  const size_t base = (size_t)bh * (SS * HDD);

  // stage the block's v tile first (independent of the colsum stream)
  {
    const float4* vsrc4 = (const float4*)(vf + ((size_t)bh * SS + bx * 128) * HDD);
    ((float4*)vstage)[tid]       = vsrc4[tid];
    ((float4*)vstage)[tid + 256] = vsrc4[tid + 256];
  }

  const bfrag kf = *(const bfrag*)(kb + base + (size_t)(t0 + l31) * HDD + hl * 8);
  const u16* qpc = qb + base + (size_t)l31 * HDD + hl * 8;
  const floatx16 z16 = {0.f};
  float c0 = 0.f, c1 = 0.f, c2 = 0.f, c3 = 0.f;

#define LQ(i) (*(const bfrag*)(qpc + (size_t)(i) * (32 * HDD)))
#define ACCUM(dv)                                   \
  do {                                              \
    _Pragma("unroll")                               \
    for (int j = 0; j < 4; ++j) {                   \
      c0 += fexp2((dv)[4 * j + 0]);                 \
      c1 += fexp2((dv)[4 * j + 1]);                 \
      c2 += fexp2((dv)[4 * j + 2]);                 \
      c3 += fexp2((dv)[4 * j + 3]);                 \
    }                                               \
  } while (0)

  bfrag q0 = LQ(0), q1 = LQ(1), q2v = LQ(2), q3 = LQ(3);
#pragma unroll 1
  for (int o = 0; o < 4; ++o) {          // rolled: keeps body ~9KB in I-cache
#pragma unroll
    for (int i = 0; i < 32; i += 4) {
      // tail prefetches over-read <=4 tiles past the bh region (lands in kb
      // workspace, values unused) -- harmless, keeps all indices static.
      {
        floatx16 d = __builtin_amdgcn_mfma_f32_32x32x16_bf16(q0, kf, z16, 0, 0, 0);
        q0 = LQ(i + 4);  ACCUM(d);
      }
      {
        floatx16 d = __builtin_amdgcn_mfma_f32_32x32x16_bf16(q1, kf, z16, 0, 0, 0);
        q1 = LQ(i + 5);  ACCUM(d);
      }
      {
        floatx16 d = __builtin_amdgcn_mfma_f32_32x32x16_bf16(q2v, kf, z16, 0, 0, 0);
        q2v = LQ(i + 6); ACCUM(d);
      }
      {
        floatx16 d = __builtin_amdgcn_mfma_f32_32x32x16_bf16(q3, kf, z16, 0, 0, 0);
        q3 = LQ(i + 7);  ACCUM(d);
      }
    }
    qpc += 32 * 32 * HDD;
  }
#undef LQ
#undef ACCUM

  float c = (c0 + c1) + (c2 + c3);
  c += __shfl_xor(c, 32, 64);
  if (hl == 0)
    rcl[w * 32 + l31] = frcp(c);
  __syncthreads();

  // pack phase: thread -> (e, poff); block owns half-chunk h0 = bx&1.
  const int e = tid >> 4;                          // 0..15
  const int h0 = bx & 1;
  const int poff = h0 * 16 + (tid & 15);           // write cc-position in chunk
  const int cc = poff ^ (e & 7);                   // source column block (same half)
  const int h128 = h0 * 128;
  u32 r[4];
#pragma unroll
  for (int jj = 0; jj < 4; ++jj) {
    int ta = tmap(cc * 8 + 2 * jj)     - h128;     // local t within block's 128
    int tb = tmap(cc * 8 + 2 * jj + 1) - h128;
    u16 lo = f2bf(vstage[ta * 16 + e] * rcl[ta]);
    u16 hi = f2bf(vstage[tb * 16 + e] * rcl[tb]);
    r[jj] = (u32)lo | ((u32)hi << 16);
  }
  u16* outb = vp + ((size_t)bh * 16 + (bx >> 1)) * 4096;
  u32x4 vv = {r[0], r[1], r[2], r[3]};
  *(u32x4*)(outb + e * 256 + poff * 8) = vv;
}

// ---------------------------------------------------------------------------
// K3: attended partials = E @ v' over a 2048-t half: eight 256-t chunks,
// double-buffered via global_load_lds (zero-VALU v staging) + rolling 8-slot
// kf register prefetch (each iter consumes kfr[it] then issues next chunk's
// load into the slot -> ~1 chunk of compute covers the L2 latency).
// Inner loop per 32 t: 1 score MFMA D'[t][s], 16 v_exp, 8 v_perm packs,
// 2 swizzled ds_read_b128, 2 PV MFMA.
// LDS 16.4 KB; grid 1024 = 4 blocks/CU exact; lb(256,4) -> 128-reg budget.
// ---------------------------------------------------------------------------
__global__ __launch_bounds__(256, 4) void k_attn(
    const u16* __restrict__ qb, const u16* __restrict__ kb,
    const u16* __restrict__ vp, float* __restrict__ attp)
{
  __shared__ __align__(16) u16 vls[2][4096];       // 2 x 8 KB
  const int tid  = threadIdx.x;
  const int lane = tid & 63, w = tid >> 6;
  const int l31 = lane & 31, hl = lane >> 5;
  const int bh = blockIdx.z, b = bh >> 2, h = bh & 3;
  const int tph = blockIdx.y;                      // 0..1 (t-half)
  const int s0 = blockIdx.x * 128 + w * 32;
  const size_t base = (size_t)bh * (SS * HDD);

  const bfrag qf = *(const bfrag*)(qb + base + (size_t)(s0 + l31) * HDD + hl * 8);
  const u16* kp = kb + base + ((size_t)tph * 2048 + l31) * HDD + hl * 8;
  const floatx16 z16 = {0.f};
  floatx16 acc = {0.f};

  const u16* vsrc = vp + ((size_t)bh * 16 + tph * 8) * 4096;

  // stage chunk 0: wave w covers u16 [w*1024, w*1024+1024)
  {
    const u16* gs = vsrc + w * 1024 + lane * 8;
    u16* ls = &vls[0][0] + w * 1024;
    gload_lds16(gs, ls);
    gload_lds16(gs + 512, ls + 512);
  }
  // prefetch chunk 0's eight kf fragments into registers
  bfrag kfr[8];
#pragma unroll
  for (int it = 0; it < 8; ++it)
    kfr[it] = *(const bfrag*)(kp + (size_t)(it * 32) * HDD);
  __syncthreads();

#pragma unroll
  for (int ch = 0; ch < 8; ++ch) {
    // DMA next chunk into the other buffer (lands before the end barrier)
    if (ch < 7) {
      const u16* gs = vsrc + (ch + 1) * 4096 + w * 1024 + lane * 8;
      u16* ls = &vls[(ch + 1) & 1][0] + w * 1024;
      gload_lds16(gs, ls);
      gload_lds16(gs + 512, ls + 512);
    }

    const u16* vrow = &vls[ch & 1][0] + (l31 & 15) * 256;
    const int eb = l31 & 7;
#pragma unroll
    for (int it = 0; it < 8; ++it) {
      bfrag kf = kfr[it];
      if (ch < 7)    // rolling prefetch: next chunk's fragment, same slot
        kfr[it] = *(const bfrag*)(kp + (size_t)((ch + 1) * 256 + it * 32) * HDD);
      floatx16 d = __builtin_amdgcn_mfma_f32_32x32x16_bf16(kf, qf, z16, 0, 0, 0);
      u32 wr[8];
#pragma unroll
      for (int p = 0; p < 8; ++p)
        wr[p] = pack_bf(fexp2(d[2 * p]), fexp2(d[2 * p + 1]));
      const int cc0 = it * 4 + hl * 2;
      u32x4 af0 = *(const u32x4*)(vrow + ((cc0 ^ eb) << 3));
      u32x4 af1 = *(const u32x4*)(vrow + (((cc0 + 1) ^ eb) << 3));
      u32x4 ef0 = {wr[0], wr[1], wr[2], wr[3]};
      u32x4 ef1 = {wr[4], wr[5], wr[6], wr[7]};
      acc = __builtin_amdgcn_mfma_f32_32x32x16_bf16(
          __builtin_bit_cast(bfrag, af0), __builtin_bit_cast(bfrag, ef0), acc, 0, 0, 0);
      acc = __builtin_amdgcn_mfma_f32_32x32x16_bf16(
          __builtin_bit_cast(bfrag, af1), __builtin_bit_cast(bfrag, ef1), acc, 0, 0, 0);
    }
    __syncthreads();   // drains vmcnt -> next chunk's DMA is in LDS
  }

  // D[e][s]: col=l31 -> s; rows r=0..3 -> e=4hl+r, r=4..7 -> e=8+4hl+(r-4)
  float* ao = attp + (((size_t)tph * BB + b) * SS + s0 + l31) * (HH * HDD)
            + h * HDD + 4 * hl;
  float4 lo4 = {acc[0], acc[1], acc[2], acc[3]};
  float4 hi4 = {acc[4], acc[5], acc[6], acc[7]};
  *(float4*)ao       = lo4;
  *(float4*)(ao + 8) = hi4;
}

// ---------------------------------------------------------------------------
// K4: out_pre = (sum of 2 attended partials) @ Wo + bo, fused partial expsum
// over each block's 8 rows -> part[b][512][64].  Wo staged in LDS.
// ---------------------------------------------------------------------------
__global__ __launch_bounds__(256) void k_oproj(
    const float* __restrict__ att, const float* __restrict__ Wo,
    const float* __restrict__ bo, float* __restrict__ outp,
    float* __restrict__ part)
{
  __shared__ float wols[64 * 64];
  __shared__ float red[4][64];
  const int tid = threadIdx.x;
  const int blk = blockIdx.x;            // 2048
  const int b = blk >> 9, s0 = (blk & 511) << 3;
#pragma unroll
  for (int i = 0; i < 4; ++i)
    ((float4*)wols)[tid + 256 * i] = ((const float4*)Wo)[tid + 256 * i];
  __syncthreads();

  const int d = tid & 63, sg = tid >> 6;
  const float bov = bo[d];
  const size_t so = (size_t)BB * SS * 16;   // t-half stride in floatx4 units
  float es = 0.f;
#pragma unroll
  for (int r = 0; r < 2; ++r) {
    int s = s0 + sg * 2 + r;
    const floatx4* row = (const floatx4*)(att + ((size_t)b * SS + s) * 64);
    float acc = bov;
#pragma unroll
    for (int j = 0; j < 16; ++j) {
      floatx4 c = row[j] + row[j + so];
      acc += c[0] * wols[(4*j+0)*64 + d] + c[1] * wols[(4*j+1)*64 + d]
           + c[2] * wols[(4*j+2)*64 + d] + c[3] * wols[(4*j+3)*64 + d];
    }
    outp[((size_t)b * SS + s) * 64 + d] = acc;
    es += fexp2(acc * LOG2E);
  }
  red[sg][d] = es;
  __syncthreads();
  if (tid < 64)
    part[((size_t)b * 512 + (blk & 511)) * 64 + tid] =
        red[0][tid] + red[1][tid] + red[2][tid] + red[3][tid];
}

// ---------------------------------------------------------------------------
// K5: out = exp(out_pre) * rcp(sum_s exp(out_pre))  (512 partials per (b,d))
// ---------------------------------------------------------------------------
__global__ __launch_bounds__(256) void k_softmax(
    const float* __restrict__ outp, const float* __restrict__ part,
    float* __restrict__ out)
{
  __shared__ float red[4][64];
  __shared__ float rs[64];
  const int tid = threadIdx.x, d = tid & 63, sg = tid >> 6;
  const int st = blockIdx.x;             // 64 s-tiles of 64
  const int b = blockIdx.y;
  {
    float e = 0.f;
    const float* pp = part + ((size_t)b * 512 + sg * 128) * 64 + d;
#pragma unroll 8
    for (int c = 0; c < 128; ++c) e += pp[c * 64];
    red[sg][d] = e;
  }
  __syncthreads();
  if (tid < 64)
    rs[tid] = frcp(red[0][tid] + red[1][tid] + red[2][tid] + red[3][tid]);
  __syncthreads();
  const float r = rs[d];
  const size_t rowbase = ((size_t)b * SS + st * 64 + sg * 16) * 64 + d;
#pragma unroll 4
  for (int i = 0; i < 16; ++i)
    out[rowbase + i * 64] = fexp2(outp[rowbase + i * 64] * LOG2E) * r;
}

// ---------------------------------------------------------------------------
extern "C" void kernel_launch(void* const* d_in, const int* in_sizes, int n_in,
                              void* d_out, int out_size, void* d_ws, size_t ws_size,
                              hipStream_t stream) {
  const float* x  = (const float*)d_in[0];
  const float* Wq = (const float*)d_in[1];
  const float* bq = (const float*)d_in[2];
  const float* Wk = (const float*)d_in[3];
  const float* bk = (const float*)d_in[4];
  const float* Wv = (const float*)d_in[5];
  const float* bv = (const float*)d_in[6];
  const float* Wo = (const float*)d_in[7];
  const float* bo = (const float*)d_in[8];

  char* ws = (char*)d_ws;
  constexpr size_t QB_OFF  = 0;                    // 2 MiB u16
  constexpr size_t KB_OFF  = (size_t)2  << 20;     // 2 MiB u16
  constexpr size_t VF_OFF  = (size_t)4  << 20;     // 4 MiB f32
  constexpr size_t VP_OFF  = (size_t)8  << 20;     // 2 MiB u16 (v' fragments)
  constexpr size_t ATT_OFF = (size_t)10 << 20;     // 8 MiB f32 (2 partials)
  constexpr size_t OUT_OFF = (size_t)18 << 20;     // 4 MiB f32
  constexpr size_t PT_OFF  = (size_t)22 << 20;     // 512 KiB f32

  u16*   qb   = (u16*)  (ws + QB_OFF);
  u16*   kb   = (u16*)  (ws + KB_OFF);
  float* vf   = (float*)(ws + VF_OFF);
  u16*   vpb  = (u16*)  (ws + VP_OFF);
  float* attp = (float*)(ws + ATT_OFF);
  float* outp = (float*)(ws + OUT_OFF);
  float* part = (float*)(ws + PT_OFF);
  float* out  = (float*)d_out;

  hipLaunchKernelGGL(k_proj,    dim3(1024),       dim3(256), 0, stream,
                     x, Wq, bq, Wk, bk, Wv, bv, qb, kb, vf);
  hipLaunchKernelGGL(k_csvp,    dim3(32, 16),     dim3(256), 0, stream,
                     qb, kb, vf, vpb);
  hipLaunchKernelGGL(k_attn,    dim3(32, 2, 16),  dim3(256), 0, stream,
                     qb, kb, vpb, attp);
  hipLaunchKernelGGL(k_oproj,   dim3(2048),       dim3(256), 0, stream,
                     attp, Wo, bo, outp, part);
  hipLaunchKernelGGL(k_softmax, dim3(64, 4),      dim3(256), 0, stream, outp, part, out);
}

// Round 5
// 183.032 us; speedup vs baseline: 1.0093x; 1.0093x over previous
//
#include <hip/hip_runtime.h>
#include <hip/hip_bf16.h>

// MultiHeadAttention B=4,S=4096,D=64,H=4,HD=16 on gfx950.
// softmax over QUERY axis => w[s,t] = E[s,t]/colsum[t], attended = E @ (V/colsum).
// Two MFMA passes recompute E (raw v_exp_f32).  Scores via 32x32x16 bf16 MFMA
// (K=16=HD exact).  PV consumes E directly as the B-operand; the implied k->t
// permutation is absorbed by pre-permuting v' in GLOBAL memory.
// R14: VALUBusy pinned ~47% at BOTH 30% and 47% occupancy => per-wave serial
// chain (scoreMFMA latency -> 16 dependent v_exp -> pack -> PV), not TLP.
// Fix: 1-deep score-MFMA ping-pong (dA/dB) in k_attn AND k_csvp -- issue the
// NEXT score MFMA (reg-only operands) before consuming the current d, fully
// unrolled so all indices are static.  k_csvp also moves to 512-thr blocks
// with s-split-2 per wave (4 waves/SIMD, double R13) + LDS partial combine.

#define BB 4
#define SS 4096
#define DD 64
#define HH 4
#define HDD 16

typedef unsigned int u32;
typedef unsigned short u16;
typedef __attribute__((ext_vector_type(8))) short bfrag;     // 8 bf16
typedef __attribute__((ext_vector_type(4))) float floatx4;
typedef __attribute__((ext_vector_type(16))) float floatx16;
typedef __attribute__((ext_vector_type(2))) u32 u32x2;
typedef __attribute__((ext_vector_type(4))) u32 u32x4;

#define LOG2E 1.4426950408889634074f
#define QSCALE (LOG2E * 0.25f)

__device__ __forceinline__ float fexp2(float x) {   // raw v_exp_f32
#if __has_builtin(__builtin_amdgcn_exp2f)
  return __builtin_amdgcn_exp2f(x);
#else
  float r; asm("v_exp_f32 %0, %1" : "=v"(r) : "v"(x)); return r;
#endif
}
__device__ __forceinline__ float frcp(float x) {    // raw v_rcp_f32
#if __has_builtin(__builtin_amdgcn_rcpf)
  return __builtin_amdgcn_rcpf(x);
#else
  float r; asm("v_rcp_f32 %0, %1" : "=v"(r) : "v"(x)); return r;
#endif
}

__device__ __forceinline__ u16 f2bf(float f) {      // RNE
  u32 u = __builtin_bit_cast(u32, f);
  return (u16)((u + 0x7FFFu + ((u >> 16) & 1u)) >> 16);
}
// pack two fp32 -> bf16x2 by truncation (E>=0), single v_perm_b32
__device__ __forceinline__ u32 pack_bf(float lo, float hi) {
#if __has_builtin(__builtin_amdgcn_perm)
  return __builtin_amdgcn_perm(__builtin_bit_cast(u32, hi),
                               __builtin_bit_cast(u32, lo), 0x07060302u);
#else
  u32 a = __builtin_bit_cast(u32, lo);
  u32 b = __builtin_bit_cast(u32, hi);
  return (a >> 16) | (b & 0xFFFF0000u);
#endif
}

// global -> LDS DMA, 16B per lane.  LDS dest = wave-uniform base + lane*16.
__device__ __forceinline__ void gload_lds16(const u16* g, u16* l) {
  __builtin_amdgcn_global_load_lds(
      (const __attribute__((address_space(1))) void*)(g),
      (__attribute__((address_space(3))) void*)(l), 16, 0, 0);
}

// fragment column c (0..255 within a 256-t chunk) -> t within chunk.
__device__ __forceinline__ int tmap(int c) {
  int c5 = c & 31;
  return (c & ~31) + (c5 & 3) + ((c5 >> 2) & 1) * 8 + ((c5 >> 3) & 1) * 16
       + ((c5 >> 4) & 1) * 4;
}

// ---------------------------------------------------------------------------
// K1: projections. x[B,S,64] -> q bf16 (scaled, bias folded), k bf16, v fp32;
// layout [B,H,S,16].
// ---------------------------------------------------------------------------
__global__ __launch_bounds__(256) void k_proj(
    const float* __restrict__ x,
    const float* __restrict__ Wq, const float* __restrict__ bq,
    const float* __restrict__ Wk, const float* __restrict__ bk,
    const float* __restrict__ Wv, const float* __restrict__ bv,
    u16* __restrict__ qb, u16* __restrict__ kb, float* __restrict__ vf)
{
  __shared__ float xs[16 * 64];
  const int tid = threadIdx.x;
  const int blk = blockIdx.x;            // B*S/16 = 1024
  const int b   = blk >> 8;
  const int s0  = (blk & 255) << 4;
  ((float4*)xs)[tid] = ((const float4*)(x + ((size_t)b * SS + s0) * DD))[tid];
  __syncthreads();

  const int col = tid & 63, h = col >> 4, e = col & 15;
  const int rg  = tid >> 6;              // wave id; 4 rows each
  float aq[4] = {0,0,0,0}, ak[4] = {0,0,0,0}, av[4] = {0,0,0,0};
  const int wofs = h * (DD * HDD) + e;
#pragma unroll 4
  for (int d = 0; d < DD; ++d) {
    float wq = Wq[wofs + d * HDD];
    float wk = Wk[wofs + d * HDD];
    float wv = Wv[wofs + d * HDD];
    const float* xr = xs + (rg * 4) * 64 + d;
#pragma unroll
    for (int r = 0; r < 4; ++r) {
      float xv = xr[r * 64];
      aq[r] += xv * wq; ak[r] += xv * wk; av[r] += xv * wv;
    }
  }
  const float bqv = bq[col], bkv = bk[col], bvv = bv[col];
  size_t base = ((size_t)(b * HH + h) * SS + (s0 + rg * 4)) * HDD + e;
#pragma unroll
  for (int r = 0; r < 4; ++r) {
    qb[base + r * HDD] = f2bf((aq[r] + bqv) * QSCALE);
    kb[base + r * HDD] = f2bf(ak[r] + bkv);
    vf[base + r * HDD] = av[r] + bvv;
  }
}

// ---------------------------------------------------------------------------
// K2: fused colsum + v'-prep, 512-thr blocks.  Wave w: t-sub = w&3 (32 t),
// s-half = w>>2 (2048 s = 64 MFMAs).  mfma(Q,K): D[m=s][n=t], col=lane&31
// -> t; s-reduction IN-LANE + shfl_xor(32); two s-half partials combined in
// LDS.  Score-MFMA ping-pong: steady-state {issue MFMA_n; refill q; ACCUM
// d_{n-1}} with 4 rotating NAMED q regs (stream tail over-reads <=5 tiles
// into the next bh region / kb -- in-bounds garbage, never ACCUMed).
// Pack phase (threads 0..255) emits the swizzled/packed v' half-chunk:
// vp[bh][chunk256][flat4096], flat = e*256 + (cc^(e&7))*8 + j, c = cc*8+j,
// t = tmap(c).
// ---------------------------------------------------------------------------
__global__ __launch_bounds__(512, 4) void k_csvp(
    const u16* __restrict__ qb, const u16* __restrict__ kb,
    const float* __restrict__ vf, u16* __restrict__ vp)
{
  __shared__ float vstage[128 * 16];     // [tl][e], 8 KB
  __shared__ float cpart[2][128];
  __shared__ float rcl[128];
  const int tid = threadIdx.x;
  const int lane = tid & 63, w = tid >> 6;
  const int l31 = lane & 31, hl = lane >> 5;
  const int bx = blockIdx.x;             // 32 t-blocks of 128
  const int bh = blockIdx.y;             // 16
  const int t0 = bx * 128 + (w & 3) * 32;
  const int shalf = w >> 2;
  const size_t base = (size_t)bh * (SS * HDD);

  // stage the block's v tile (independent of the colsum stream)
  {
    const float4* vsrc4 = (const float4*)(vf + ((size_t)bh * SS + bx * 128) * HDD);
    ((float4*)vstage)[tid] = vsrc4[tid];
  }

  const bfrag kf = *(const bfrag*)(kb + base + (size_t)(t0 + l31) * HDD + hl * 8);
  const u16* qpc = qb + base + ((size_t)shalf * 2048 + l31) * HDD + hl * 8;
  const floatx16 z16 = {0.f};
  float c0 = 0.f, c1 = 0.f, c2 = 0.f, c3 = 0.f;

#define LQ(i) (*(const bfrag*)(qpc + (size_t)(i) * (32 * HDD)))
#define ACCUM(dv)                                   \
  do {                                              \
    _Pragma("unroll")                               \
    for (int j = 0; j < 4; ++j) {                   \
      c0 += fexp2((dv)[4 * j + 0]);                 \
      c1 += fexp2((dv)[4 * j + 1]);                 \
      c2 += fexp2((dv)[4 * j + 2]);                 \
      c3 += fexp2((dv)[4 * j + 3]);                 \
    }                                               \
  } while (0)
#define STEP(qr, ri)                                                        \
  do {                                                                      \
    floatx16 dB = __builtin_amdgcn_mfma_f32_32x32x16_bf16(qr, kf, z16, 0, 0, 0); \
    qr = LQ(ri);                                                            \
    ACCUM(dA);                                                              \
    dA = dB;                                                                \
  } while (0)

  bfrag q0 = LQ(0), q1 = LQ(1), q2v = LQ(2), q3 = LQ(3);
  floatx16 dA = __builtin_amdgcn_mfma_f32_32x32x16_bf16(q0, kf, z16, 0, 0, 0);
  q0 = LQ(4);
#pragma unroll 1
  for (int o = 0; o < 2; ++o) {          // rolled: I-cache
#pragma unroll
    for (int i = 0; i < 32; i += 4) {
      STEP(q1,  i + 5);
      STEP(q2v, i + 6);
      STEP(q3,  i + 7);
      STEP(q0,  i + 8);
    }
    qpc += 32 * 32 * HDD;
  }
#undef STEP
#undef LQ
#undef ACCUM

  float c = (c0 + c1) + (c2 + c3);
  c += __shfl_xor(c, 32, 64);
  if (hl == 0)
    cpart[shalf][(w & 3) * 32 + l31] = c;
  __syncthreads();
  if (tid < 128)
    rcl[tid] = frcp(cpart[0][tid] + cpart[1][tid]);
  __syncthreads();

  // pack phase: threads 0..255 -> (e, poff); block owns half-chunk h0 = bx&1.
  if (tid < 256) {
    const int e = tid >> 4;                          // 0..15
    const int h0 = bx & 1;
    const int poff = h0 * 16 + (tid & 15);           // write cc-position
    const int cc = poff ^ (e & 7);                   // source column block
    const int h128 = h0 * 128;
    u32 r[4];
#pragma unroll
    for (int jj = 0; jj < 4; ++jj) {
      int ta = tmap(cc * 8 + 2 * jj)     - h128;     // local t within 128
      int tb = tmap(cc * 8 + 2 * jj + 1) - h128;
      u16 lo = f2bf(vstage[ta * 16 + e] * rcl[ta]);
      u16 hi = f2bf(vstage[tb * 16 + e] * rcl[tb]);
      r[jj] = (u32)lo | ((u32)hi << 16);
    }
    u16* outb = vp + ((size_t)bh * 16 + (bx >> 1)) * 4096;
    u32x4 vv = {r[0], r[1], r[2], r[3]};
    *(u32x4*)(outb + e * 256 + poff * 8) = vv;
  }
}

// ---------------------------------------------------------------------------
// K3: attended partials = E @ v' over a 2048-t half: eight 256-t chunks,
// double-buffered via global_load_lds (zero-VALU v staging) + rolling 8-slot
// kf register prefetch + score-MFMA ping-pong: the NEXT score MFMA (reg-only)
// issues BEFORE the current d's exp/pack/PV chain, including across chunk
// barriers.  Inner iter per 32 t: 1 score MFMA (pipelined), 16 v_exp,
// 8 v_perm packs, 2 swizzled ds_read_b128, 2 PV MFMA.
// LDS 16.4 KB; grid 1024 = 4 blocks/CU exact; lb(256,4) -> 128-reg budget.
// ---------------------------------------------------------------------------
__global__ __launch_bounds__(256, 4) void k_attn(
    const u16* __restrict__ qb, const u16* __restrict__ kb,
    const u16* __restrict__ vp, float* __restrict__ attp)
{
  __shared__ __align__(16) u16 vls[2][4096];       // 2 x 8 KB
  const int tid  = threadIdx.x;
  const int lane = tid & 63, w = tid >> 6;
  const int l31 = lane & 31, hl = lane >> 5;
  const int bh = blockIdx.z, b = bh >> 2, h = bh & 3;
  const int tph = blockIdx.y;                      // 0..1 (t-half)
  const int s0 = blockIdx.x * 128 + w * 32;
  const size_t base = (size_t)bh * (SS * HDD);

  const bfrag qf = *(const bfrag*)(qb + base + (size_t)(s0 + l31) * HDD + hl * 8);
  const u16* kp = kb + base + ((size_t)tph * 2048 + l31) * HDD + hl * 8;
  const floatx16 z16 = {0.f};
  floatx16 acc = {0.f};

  const u16* vsrc = vp + ((size_t)bh * 16 + tph * 8) * 4096;

  // stage chunk 0: wave w covers u16 [w*1024, w*1024+1024)
  {
    const u16* gs = vsrc + w * 1024 + lane * 8;
    u16* ls = &vls[0][0] + w * 1024;
    gload_lds16(gs, ls);
    gload_lds16(gs + 512, ls + 512);
  }
  // prefetch chunk 0's eight kf fragments into registers
  bfrag kfr[8];
#pragma unroll
  for (int it = 0; it < 8; ++it)
    kfr[it] = *(const bfrag*)(kp + (size_t)(it * 32) * HDD);
  // pipeline prologue: issue score (0,0) -- reg-only, legal before barrier
  floatx16 dA = __builtin_amdgcn_mfma_f32_32x32x16_bf16(kfr[0], qf, z16, 0, 0, 0);
  __syncthreads();

#pragma unroll
  for (int ch = 0; ch < 8; ++ch) {
    // DMA next chunk into the other buffer (lands before the end barrier)
    if (ch < 7) {
      const u16* gs = vsrc + (ch + 1) * 4096 + w * 1024 + lane * 8;
      u16* ls = &vls[(ch + 1) & 1][0] + w * 1024;
      gload_lds16(gs, ls);
      gload_lds16(gs + 512, ls + 512);
    }

    const u16* vrow = &vls[ch & 1][0] + (l31 & 15) * 256;
    const int eb = l31 & 7;
#pragma unroll
    for (int it = 0; it < 8; ++it) {
      // refill this slot with next chunk's fragment (slot free: its score
      // for THIS chunk was already issued -- it=0 in the prologue / at the
      // previous iteration's ping-pong)
      if (ch < 7)
        kfr[it] = *(const bfrag*)(kp + (size_t)((ch + 1) * 256 + it * 32) * HDD);
      // issue NEXT score MFMA before consuming dA (ping-pong)
      floatx16 dB;
      if (ch == 7 && it == 7) {
        dB = dA;
      } else {
        bfrag kn = (it < 7) ? kfr[it + 1] : kfr[0];   // it==7: refilled ch+1,0
        dB = __builtin_amdgcn_mfma_f32_32x32x16_bf16(kn, qf, z16, 0, 0, 0);
      }
      // consume dA = score (ch, it)
      u32 wr[8];
#pragma unroll
      for (int p = 0; p < 8; ++p)
        wr[p] = pack_bf(fexp2(dA[2 * p]), fexp2(dA[2 * p + 1]));
      const int cc0 = it * 4 + hl * 2;
      u32x4 af0 = *(const u32x4*)(vrow + ((cc0 ^ eb) << 3));
      u32x4 af1 = *(const u32x4*)(vrow + (((cc0 + 1) ^ eb) << 3));
      u32x4 ef0 = {wr[0], wr[1], wr[2], wr[3]};
      u32x4 ef1 = {wr[4], wr[5], wr[6], wr[7]};
      acc = __builtin_amdgcn_mfma_f32_32x32x16_bf16(
          __builtin_bit_cast(bfrag, af0), __builtin_bit_cast(bfrag, ef0), acc, 0, 0, 0);
      acc = __builtin_amdgcn_mfma_f32_32x32x16_bf16(
          __builtin_bit_cast(bfrag, af1), __builtin_bit_cast(bfrag, ef1), acc, 0, 0, 0);
      dA = dB;
    }
    __syncthreads();   // drains vmcnt -> next chunk's DMA is in LDS
  }

  // D[e][s]: col=l31 -> s; rows r=0..3 -> e=4hl+r, r=4..7 -> e=8+4hl+(r-4)
  float* ao = attp + (((size_t)tph * BB + b) * SS + s0 + l31) * (HH * HDD)
            + h * HDD + 4 * hl;
  float4 lo4 = {acc[0], acc[1], acc[2], acc[3]};
  float4 hi4 = {acc[4], acc[5], acc[6], acc[7]};
  *(float4*)ao       = lo4;
  *(float4*)(ao + 8) = hi4;
}

// ---------------------------------------------------------------------------
// K4: out_pre = (sum of 2 attended partials) @ Wo + bo, fused partial expsum
// over each block's 8 rows -> part[b][512][64].  Wo staged in LDS.
// ---------------------------------------------------------------------------
__global__ __launch_bounds__(256) void k_oproj(
    const float* __restrict__ att, const float* __restrict__ Wo,
    const float* __restrict__ bo, float* __restrict__ outp,
    float* __restrict__ part)
{
  __shared__ float wols[64 * 64];
  __shared__ float red[4][64];
  const int tid = threadIdx.x;
  const int blk = blockIdx.x;            // 2048
  const int b = blk >> 9, s0 = (blk & 511) << 3;
#pragma unroll
  for (int i = 0; i < 4; ++i)
    ((float4*)wols)[tid + 256 * i] = ((const float4*)Wo)[tid + 256 * i];
  __syncthreads();

  const int d = tid & 63, sg = tid >> 6;
  const float bov = bo[d];
  const size_t so = (size_t)BB * SS * 16;   // t-half stride in floatx4 units
  float es = 0.f;
#pragma unroll
  for (int r = 0; r < 2; ++r) {
    int s = s0 + sg * 2 + r;
    const floatx4* row = (const floatx4*)(att + ((size_t)b * SS + s) * 64);
    float acc = bov;
#pragma unroll
    for (int j = 0; j < 16; ++j) {
      floatx4 c = row[j] + row[j + so];
      acc += c[0] * wols[(4*j+0)*64 + d] + c[1] * wols[(4*j+1)*64 + d]
           + c[2] * wols[(4*j+2)*64 + d] + c[3] * wols[(4*j+3)*64 + d];
    }
    outp[((size_t)b * SS + s) * 64 + d] = acc;
    es += fexp2(acc * LOG2E);
  }
  red[sg][d] = es;
  __syncthreads();
  if (tid < 64)
    part[((size_t)b * 512 + (blk & 511)) * 64 + tid] =
        red[0][tid] + red[1][tid] + red[2][tid] + red[3][tid];
}

// ---------------------------------------------------------------------------
// K5: out = exp(out_pre) * rcp(sum_s exp(out_pre))  (512 partials per (b,d))
// ---------------------------------------------------------------------------
__global__ __launch_bounds__(256) void k_softmax(
    const float* __restrict__ outp, const float* __restrict__ part,
    float* __restrict__ out)
{
  __shared__ float red[4][64];
  __shared__ float rs[64];
  const int tid = threadIdx.x, d = tid & 63, sg = tid >> 6;
  const int st = blockIdx.x;             // 64 s-tiles of 64
  const int b = blockIdx.y;
  {
    float e = 0.f;
    const float* pp = part + ((size_t)b * 512 + sg * 128) * 64 + d;
#pragma unroll 8
    for (int c = 0; c < 128; ++c) e += pp[c * 64];
    red[sg][d] = e;
  }
  __syncthreads();
  if (tid < 64)
    rs[tid] = frcp(red[0][tid] + red[1][tid] + red[2][tid] + red[3][tid]);
  __syncthreads();
  const float r = rs[d];
  const size_t rowbase = ((size_t)b * SS + st * 64 + sg * 16) * 64 + d;
#pragma unroll 4
  for (int i = 0; i < 16; ++i)
    out[rowbase + i * 64] = fexp2(outp[rowbase + i * 64] * LOG2E) * r;
}

// ---------------------------------------------------------------------------
extern "C" void kernel_launch(void* const* d_in, const int* in_sizes, int n_in,
                              void* d_out, int out_size, void* d_ws, size_t ws_size,
                              hipStream_t stream) {
  const float* x  = (const float*)d_in[0];
  const float* Wq = (const float*)d_in[1];
  const float* bq = (const float*)d_in[2];
  const float* Wk = (const float*)d_in[3];
  const float* bk = (const float*)d_in[4];
  const float* Wv = (const float*)d_in[5];
  const float* bv = (const float*)d_in[6];
  const float* Wo = (const float*)d_in[7];
  const float* bo = (const float*)d_in[8];

  char* ws = (char*)d_ws;
  constexpr size_t QB_OFF  = 0;                    // 2 MiB u16
  constexpr size_t KB_OFF  = (size_t)2  << 20;     // 2 MiB u16
  constexpr size_t VF_OFF  = (size_t)4  << 20;     // 4 MiB f32
  constexpr size_t VP_OFF  = (size_t)8  << 20;     // 2 MiB u16 (v' fragments)
  constexpr size_t ATT_OFF = (size_t)10 << 20;     // 8 MiB f32 (2 partials)
  constexpr size_t OUT_OFF = (size_t)18 << 20;     // 4 MiB f32
  constexpr size_t PT_OFF  = (size_t)22 << 20;     // 512 KiB f32

  u16*   qb   = (u16*)  (ws + QB_OFF);
  u16*   kb   = (u16*)  (ws + KB_OFF);
  float* vf   = (float*)(ws + VF_OFF);
  u16*   vpb  = (u16*)  (ws + VP_OFF);
  float* attp = (float*)(ws + ATT_OFF);
  float* outp = (float*)(ws + OUT_OFF);
  float* part = (float*)(ws + PT_OFF);
  float* out  = (float*)d_out;

  hipLaunchKernelGGL(k_proj,    dim3(1024),       dim3(256), 0, stream,
                     x, Wq, bq, Wk, bk, Wv, bv, qb, kb, vf);
  hipLaunchKernelGGL(k_csvp,    dim3(32, 16),     dim3(512), 0, stream,
                     qb, kb, vf, vpb);
  hipLaunchKernelGGL(k_attn,    dim3(32, 2, 16),  dim3(256), 0, stream,
                     qb, kb, vpb, attp);
  hipLaunchKernelGGL(k_oproj,   dim3(2048),       dim3(256), 0, stream,
                     attp, Wo, bo, outp, part);
  hipLaunchKernelGGL(k_softmax, dim3(64, 4),      dim3(256), 0, stream, outp, part, out);
}

// Round 6
// 179.562 us; speedup vs baseline: 1.0288x; 1.0193x over previous
//
#include <hip/hip_runtime.h>
#include <hip/hip_bf16.h>

// MultiHeadAttention B=4,S=4096,D=64,H=4,HD=16 on gfx950.
// softmax over QUERY axis => w[s,t] = E[s,t]/colsum[t], attended = E @ (V/colsum).
// Two MFMA passes recompute E (raw v_exp_f32).  Scores via 32x32x16 bf16 MFMA
// (K=16=HD exact).  PV consumes E directly as the B-operand; the implied k->t
// permutation is absorbed by pre-permuting v' in GLOBAL memory.
// R15: k_attn was barrier-drain bound: __syncthreads() per chunk emits
// s_waitcnt vmcnt(0) draining the in-flight DMA + kf loads issued ~50cyc
// earlier -> all 4 waves lockstep-stall a full L2 roundtrip every chunk
// (measured 1630 cyc/iter vs ~616 of issue work; VALUBusy pinned 47%
// across occupancy/prefetch/ping-pong changes R1-R5).  Fix: VMEM-free inner
// loop (K also staged to LDS via new fragment-linear kfl layout; kb deleted)
// + raw s_barrier with vmcnt(0) waited one full chunk after issue (free)
// + dual PV accumulators.  k_csvp unchanged except kf reads kfl.

#define BB 4
#define SS 4096
#define DD 64
#define HH 4
#define HDD 16

typedef unsigned int u32;
typedef unsigned short u16;
typedef __attribute__((ext_vector_type(8))) short bfrag;     // 8 bf16
typedef __attribute__((ext_vector_type(4))) float floatx4;
typedef __attribute__((ext_vector_type(16))) float floatx16;
typedef __attribute__((ext_vector_type(2))) u32 u32x2;
typedef __attribute__((ext_vector_type(4))) u32 u32x4;

#define LOG2E 1.4426950408889634074f
#define QSCALE (LOG2E * 0.25f)

__device__ __forceinline__ float fexp2(float x) {   // raw v_exp_f32
#if __has_builtin(__builtin_amdgcn_exp2f)
  return __builtin_amdgcn_exp2f(x);
#else
  float r; asm("v_exp_f32 %0, %1" : "=v"(r) : "v"(x)); return r;
#endif
}
__device__ __forceinline__ float frcp(float x) {    // raw v_rcp_f32
#if __has_builtin(__builtin_amdgcn_rcpf)
  return __builtin_amdgcn_rcpf(x);
#else
  float r; asm("v_rcp_f32 %0, %1" : "=v"(r) : "v"(x)); return r;
#endif
}

__device__ __forceinline__ u16 f2bf(float f) {      // RNE
  u32 u = __builtin_bit_cast(u32, f);
  return (u16)((u + 0x7FFFu + ((u >> 16) & 1u)) >> 16);
}
// pack two fp32 -> bf16x2 by truncation (E>=0), single v_perm_b32
__device__ __forceinline__ u32 pack_bf(float lo, float hi) {
#if __has_builtin(__builtin_amdgcn_perm)
  return __builtin_amdgcn_perm(__builtin_bit_cast(u32, hi),
                               __builtin_bit_cast(u32, lo), 0x07060302u);
#else
  u32 a = __builtin_bit_cast(u32, lo);
  u32 b = __builtin_bit_cast(u32, hi);
  return (a >> 16) | (b & 0xFFFF0000u);
#endif
}

// global -> LDS DMA, 16B per lane.  LDS dest = wave-uniform base + lane*16.
__device__ __forceinline__ void gload_lds16(const u16* g, u16* l) {
  __builtin_amdgcn_global_load_lds(
      (const __attribute__((address_space(1))) void*)(g),
      (__attribute__((address_space(3))) void*)(l), 16, 0, 0);
}

// fragment column c (0..255 within a 256-t chunk) -> t within chunk.
__device__ __forceinline__ int tmap(int c) {
  int c5 = c & 31;
  return (c & ~31) + (c5 & 3) + ((c5 >> 2) & 1) * 8 + ((c5 >> 3) & 1) * 16
       + ((c5 >> 4) & 1) * 4;
}

// ---------------------------------------------------------------------------
// K1: projections. x[B,S,64] -> q bf16 (scaled, bias folded) [B,H,S,16];
// k bf16 FRAGMENT-LINEAR kfl[bh][t/32][lane=(e>>3)*32+(t&31)][j=e&7]
// (so K chunks DMA linearly into LDS and ds_read_b128 at lane*16B is
// conflict-free); v fp32 [B,H,S,16].
// ---------------------------------------------------------------------------
__global__ __launch_bounds__(256) void k_proj(
    const float* __restrict__ x,
    const float* __restrict__ Wq, const float* __restrict__ bq,
    const float* __restrict__ Wk, const float* __restrict__ bk,
    const float* __restrict__ Wv, const float* __restrict__ bv,
    u16* __restrict__ qb, u16* __restrict__ kfl, float* __restrict__ vf)
{
  __shared__ float xs[16 * 64];
  const int tid = threadIdx.x;
  const int blk = blockIdx.x;            // B*S/16 = 1024
  const int b   = blk >> 8;
  const int s0  = (blk & 255) << 4;
  ((float4*)xs)[tid] = ((const float4*)(x + ((size_t)b * SS + s0) * DD))[tid];
  __syncthreads();

  const int col = tid & 63, h = col >> 4, e = col & 15;
  const int rg  = tid >> 6;              // wave id; 4 rows each
  float aq[4] = {0,0,0,0}, ak[4] = {0,0,0,0}, av[4] = {0,0,0,0};
  const int wofs = h * (DD * HDD) + e;
#pragma unroll 4
  for (int d = 0; d < DD; ++d) {
    float wq = Wq[wofs + d * HDD];
    float wk = Wk[wofs + d * HDD];
    float wv = Wv[wofs + d * HDD];
    const float* xr = xs + (rg * 4) * 64 + d;
#pragma unroll
    for (int r = 0; r < 4; ++r) {
      float xv = xr[r * 64];
      aq[r] += xv * wq; ak[r] += xv * wk; av[r] += xv * wv;
    }
  }
  const float bqv = bq[col], bkv = bk[col], bvv = bv[col];
  const int bh = b * HH + h;
  size_t base = ((size_t)bh * SS + (s0 + rg * 4)) * HDD + e;
#pragma unroll
  for (int r = 0; r < 4; ++r) {
    int t = s0 + rg * 4 + r;
    qb[base + r * HDD] = f2bf((aq[r] + bqv) * QSCALE);
    vf[base + r * HDD] = av[r] + bvv;
    size_t kidx = (((size_t)bh * 128 + (t >> 5)) * 64
                 + (e >> 3) * 32 + (t & 31)) * 8 + (e & 7);
    kfl[kidx] = f2bf(ak[r] + bkv);
  }
}

// ---------------------------------------------------------------------------
// K2: fused colsum + v'-prep, 512-thr blocks.  Wave w: t-sub = w&3 (32 t),
// s-half = w>>2 (2048 s = 64 MFMAs).  mfma(Q,K): D[m=s][n=t], col=lane&31
// -> t; s-reduction IN-LANE + shfl_xor(32); two s-half partials combined in
// LDS.  Score-MFMA ping-pong with 4 rotating NAMED q regs.  kf now reads the
// fragment-linear kfl (16B/lane contiguous).  Pack phase (threads 0..255)
// emits the swizzled/packed v' half-chunk: vp[bh][chunk256][flat4096],
// flat = e*256 + (cc^(e&7))*8 + j, c = cc*8+j, t = tmap(c).
// ---------------------------------------------------------------------------
__global__ __launch_bounds__(512, 4) void k_csvp(
    const u16* __restrict__ qb, const u16* __restrict__ kfl,
    const float* __restrict__ vf, u16* __restrict__ vp)
{
  __shared__ float vstage[128 * 16];     // [tl][e], 8 KB
  __shared__ float cpart[2][128];
  __shared__ float rcl[128];
  const int tid = threadIdx.x;
  const int lane = tid & 63, w = tid >> 6;
  const int l31 = lane & 31, hl = lane >> 5;
  const int bx = blockIdx.x;             // 32 t-blocks of 128
  const int bh = blockIdx.y;             // 16
  const int shalf = w >> 2;
  const size_t base = (size_t)bh * (SS * HDD);

  // stage the block's v tile (independent of the colsum stream)
  {
    const float4* vsrc4 = (const float4*)(vf + ((size_t)bh * SS + bx * 128) * HDD);
    ((float4*)vstage)[tid] = vsrc4[tid];
  }

  const int g = bx * 4 + (w & 3);
  const bfrag kf = *(const bfrag*)(kfl + (((size_t)bh * 128 + g) * 64 + lane) * 8);
  const u16* qpc = qb + base + ((size_t)shalf * 2048 + l31) * HDD + hl * 8;
  const floatx16 z16 = {0.f};
  float c0 = 0.f, c1 = 0.f, c2 = 0.f, c3 = 0.f;

#define LQ(i) (*(const bfrag*)(qpc + (size_t)(i) * (32 * HDD)))
#define ACCUM(dv)                                   \
  do {                                              \
    _Pragma("unroll")                               \
    for (int j = 0; j < 4; ++j) {                   \
      c0 += fexp2((dv)[4 * j + 0]);                 \
      c1 += fexp2((dv)[4 * j + 1]);                 \
      c2 += fexp2((dv)[4 * j + 2]);                 \
      c3 += fexp2((dv)[4 * j + 3]);                 \
    }                                               \
  } while (0)
#define STEP(qr, ri)                                                        \
  do {                                                                      \
    floatx16 dB = __builtin_amdgcn_mfma_f32_32x32x16_bf16(qr, kf, z16, 0, 0, 0); \
    qr = LQ(ri);                                                            \
    ACCUM(dA);                                                              \
    dA = dB;                                                                \
  } while (0)

  bfrag q0 = LQ(0), q1 = LQ(1), q2v = LQ(2), q3 = LQ(3);
  floatx16 dA = __builtin_amdgcn_mfma_f32_32x32x16_bf16(q0, kf, z16, 0, 0, 0);
  q0 = LQ(4);
#pragma unroll 1
  for (int o = 0; o < 2; ++o) {          // rolled: I-cache
#pragma unroll
    for (int i = 0; i < 32; i += 4) {
      STEP(q1,  i + 5);
      STEP(q2v, i + 6);
      STEP(q3,  i + 7);
      STEP(q0,  i + 8);
    }
    qpc += 32 * 32 * HDD;
  }
#undef STEP
#undef LQ
#undef ACCUM

  float c = (c0 + c1) + (c2 + c3);
  c += __shfl_xor(c, 32, 64);
  if (hl == 0)
    cpart[shalf][(w & 3) * 32 + l31] = c;
  __syncthreads();
  if (tid < 128)
    rcl[tid] = frcp(cpart[0][tid] + cpart[1][tid]);
  __syncthreads();

  // pack phase: threads 0..255 -> (e, poff); block owns half-chunk h0 = bx&1.
  if (tid < 256) {
    const int e = tid >> 4;                          // 0..15
    const int h0 = bx & 1;
    const int poff = h0 * 16 + (tid & 15);           // write cc-position
    const int cc = poff ^ (e & 7);                   // source column block
    const int h128 = h0 * 128;
    u32 r[4];
#pragma unroll
    for (int jj = 0; jj < 4; ++jj) {
      int ta = tmap(cc * 8 + 2 * jj)     - h128;     // local t within 128
      int tb = tmap(cc * 8 + 2 * jj + 1) - h128;
      u16 lo = f2bf(vstage[ta * 16 + e] * rcl[ta]);
      u16 hi = f2bf(vstage[tb * 16 + e] * rcl[tb]);
      r[jj] = (u32)lo | ((u32)hi << 16);
    }
    u16* outb = vp + ((size_t)bh * 16 + (bx >> 1)) * 4096;
    u32x4 vv = {r[0], r[1], r[2], r[3]};
    *(u32x4*)(outb + e * 256 + poff * 8) = vv;
  }
}

// ---------------------------------------------------------------------------
// K3: attended partials = E @ v' over a 2048-t half: eight 256-t chunks.
// Both K and v' chunks DMA into double-buffered LDS (global_load_lds) ->
// the inner loop is VMEM-FREE.  Per chunk: {vmcnt(0) [waits DMA issued a
// full chunk ago => ~free]; raw s_barrier; issue next chunk's DMA; 8 kf
// ds_read_b128 (conflict-free, lane*16B); 8 iters of score-MFMA ping-pong
// + 16 v_exp + 8 packs + 2 af ds_read + 2 PV MFMA into DUAL accumulators}.
// LDS 32.8 KB; grid 1024 = 4 blocks/CU exact; lb(256,4).
// ---------------------------------------------------------------------------
__global__ __launch_bounds__(256, 4) void k_attn(
    const u16* __restrict__ qb, const u16* __restrict__ kfl,
    const u16* __restrict__ vp, float* __restrict__ attp)
{
  __shared__ __align__(16) u16 vls[2][4096];       // 2 x 8 KB
  __shared__ __align__(16) u16 kls[2][4096];       // 2 x 8 KB
  const int tid  = threadIdx.x;
  const int lane = tid & 63, w = tid >> 6;
  const int l31 = lane & 31, hl = lane >> 5;
  const int bh = blockIdx.z, b = bh >> 2, h = bh & 3;
  const int tph = blockIdx.y;                      // 0..1 (t-half)
  const int s0 = blockIdx.x * 128 + w * 32;
  const size_t base = (size_t)bh * (SS * HDD);

  const bfrag qf = *(const bfrag*)(qb + base + (size_t)(s0 + l31) * HDD + hl * 8);
  const floatx16 z16 = {0.f};
  floatx16 acc0 = {0.f}, acc1 = {0.f};

  const u16* vsrc = vp  + ((size_t)bh * 16  + tph * 8)  * 4096;
  const u16* ksrc = kfl + ((size_t)bh * 128 + tph * 64) * 512;   // 8 grp/chunk

  // per-chunk DMA: wave w covers u16 [w*1024, w*1024+1024) of each 4096 buf
#define STAGE(ch, buf)                                                \
  do {                                                                \
    const u16* gv = vsrc + (ch) * 4096 + w * 1024 + lane * 8;         \
    u16* lv = &vls[buf][0] + w * 1024;                                \
    gload_lds16(gv, lv);                                              \
    gload_lds16(gv + 512, lv + 512);                                  \
    const u16* gk = ksrc + (ch) * 4096 + w * 1024 + lane * 8;         \
    u16* lk = &kls[buf][0] + w * 1024;                                \
    gload_lds16(gk, lk);                                              \
    gload_lds16(gk + 512, lk + 512);                                  \
  } while (0)

  STAGE(0, 0);

#pragma unroll
  for (int ch = 0; ch < 8; ++ch) {
    // my DMA for this chunk was issued a full chunk ago -> wait ~free;
    // barrier (no drain) publishes every wave's DMA and closes reads of
    // the buffer the next STAGE overwrites.
    asm volatile("s_waitcnt vmcnt(0)" ::: "memory");
    __builtin_amdgcn_s_barrier();
    __builtin_amdgcn_sched_barrier(0);
    if (ch < 7) STAGE(ch + 1, (ch + 1) & 1);

    const u16* vrow = &vls[ch & 1][0] + (l31 & 15) * 256;
    const u16* krow = &kls[ch & 1][0];
    const int eb = l31 & 7;

    bfrag kfr[4];                         // 4-slot rotation, static indices
#pragma unroll
    for (int it = 0; it < 4; ++it)
      kfr[it] = *(const bfrag*)(krow + it * 512 + lane * 8);
    floatx16 dA = __builtin_amdgcn_mfma_f32_32x32x16_bf16(kfr[0], qf, z16, 0, 0, 0);

#pragma unroll
    for (int it = 0; it < 8; ++it) {
      if (it < 4)                         // refill consumed slot with it+4
        kfr[it & 3] = *(const bfrag*)(krow + (it + 4) * 512 + lane * 8);
      floatx16 dB;
      if (it < 7)
        dB = __builtin_amdgcn_mfma_f32_32x32x16_bf16(kfr[(it + 1) & 3], qf, z16, 0, 0, 0);
      else
        dB = dA;
      // consume dA = score (ch, it)
      u32 wr[8];
#pragma unroll
      for (int p = 0; p < 8; ++p)
        wr[p] = pack_bf(fexp2(dA[2 * p]), fexp2(dA[2 * p + 1]));
      const int cc0 = it * 4 + hl * 2;
      u32x4 af0 = *(const u32x4*)(vrow + ((cc0 ^ eb) << 3));
      u32x4 af1 = *(const u32x4*)(vrow + (((cc0 + 1) ^ eb) << 3));
      u32x4 ef0 = {wr[0], wr[1], wr[2], wr[3]};
      u32x4 ef1 = {wr[4], wr[5], wr[6], wr[7]};
      acc0 = __builtin_amdgcn_mfma_f32_32x32x16_bf16(
          __builtin_bit_cast(bfrag, af0), __builtin_bit_cast(bfrag, ef0), acc0, 0, 0, 0);
      acc1 = __builtin_amdgcn_mfma_f32_32x32x16_bf16(
          __builtin_bit_cast(bfrag, af1), __builtin_bit_cast(bfrag, ef1), acc1, 0, 0, 0);
      dA = dB;
    }
  }
#undef STAGE

  floatx16 acc = acc0 + acc1;
  // D[e][s]: col=l31 -> s; rows r=0..3 -> e=4hl+r, r=4..7 -> e=8+4hl+(r-4)
  float* ao = attp + (((size_t)tph * BB + b) * SS + s0 + l31) * (HH * HDD)
            + h * HDD + 4 * hl;
  float4 lo4 = {acc[0], acc[1], acc[2], acc[3]};
  float4 hi4 = {acc[4], acc[5], acc[6], acc[7]};
  *(float4*)ao       = lo4;
  *(float4*)(ao + 8) = hi4;
}

// ---------------------------------------------------------------------------
// K4: out_pre = (sum of 2 attended partials) @ Wo + bo, fused partial expsum
// over each block's 8 rows -> part[b][512][64].  Wo staged in LDS.
// ---------------------------------------------------------------------------
__global__ __launch_bounds__(256) void k_oproj(
    const float* __restrict__ att, const float* __restrict__ Wo,
    const float* __restrict__ bo, float* __restrict__ outp,
    float* __restrict__ part)
{
  __shared__ float wols[64 * 64];
  __shared__ float red[4][64];
  const int tid = threadIdx.x;
  const int blk = blockIdx.x;            // 2048
  const int b = blk >> 9, s0 = (blk & 511) << 3;
#pragma unroll
  for (int i = 0; i < 4; ++i)
    ((float4*)wols)[tid + 256 * i] = ((const float4*)Wo)[tid + 256 * i];
  __syncthreads();

  const int d = tid & 63, sg = tid >> 6;
  const float bov = bo[d];
  const size_t so = (size_t)BB * SS * 16;   // t-half stride in floatx4 units
  float es = 0.f;
#pragma unroll
  for (int r = 0; r < 2; ++r) {
    int s = s0 + sg * 2 + r;
    const floatx4* row = (const floatx4*)(att + ((size_t)b * SS + s) * 64);
    float acc = bov;
#pragma unroll
    for (int j = 0; j < 16; ++j) {
      floatx4 c = row[j] + row[j + so];
      acc += c[0] * wols[(4*j+0)*64 + d] + c[1] * wols[(4*j+1)*64 + d]
           + c[2] * wols[(4*j+2)*64 + d] + c[3] * wols[(4*j+3)*64 + d];
    }
    outp[((size_t)b * SS + s) * 64 + d] = acc;
    es += fexp2(acc * LOG2E);
  }
  red[sg][d] = es;
  __syncthreads();
  if (tid < 64)
    part[((size_t)b * 512 + (blk & 511)) * 64 + tid] =
        red[0][tid] + red[1][tid] + red[2][tid] + red[3][tid];
}

// ---------------------------------------------------------------------------
// K5: out = exp(out_pre) * rcp(sum_s exp(out_pre))  (512 partials per (b,d))
// ---------------------------------------------------------------------------
__global__ __launch_bounds__(256) void k_softmax(
    const float* __restrict__ outp, const float* __restrict__ part,
    float* __restrict__ out)
{
  __shared__ float red[4][64];
  __shared__ float rs[64];
  const int tid = threadIdx.x, d = tid & 63, sg = tid >> 6;
  const int st = blockIdx.x;             // 64 s-tiles of 64
  const int b = blockIdx.y;
  {
    float e = 0.f;
    const float* pp = part + ((size_t)b * 512 + sg * 128) * 64 + d;
#pragma unroll 8
    for (int c = 0; c < 128; ++c) e += pp[c * 64];
    red[sg][d] = e;
  }
  __syncthreads();
  if (tid < 64)
    rs[tid] = frcp(red[0][tid] + red[1][tid] + red[2][tid] + red[3][tid]);
  __syncthreads();
  const float r = rs[d];
  const size_t rowbase = ((size_t)b * SS + st * 64 + sg * 16) * 64 + d;
#pragma unroll 4
  for (int i = 0; i < 16; ++i)
    out[rowbase + i * 64] = fexp2(outp[rowbase + i * 64] * LOG2E) * r;
}

// ---------------------------------------------------------------------------
extern "C" void kernel_launch(void* const* d_in, const int* in_sizes, int n_in,
                              void* d_out, int out_size, void* d_ws, size_t ws_size,
                              hipStream_t stream) {
  const float* x  = (const float*)d_in[0];
  const float* Wq = (const float*)d_in[1];
  const float* bq = (const float*)d_in[2];
  const float* Wk = (const float*)d_in[3];
  const float* bk = (const float*)d_in[4];
  const float* Wv = (const float*)d_in[5];
  const float* bv = (const float*)d_in[6];
  const float* Wo = (const float*)d_in[7];
  const float* bo = (const float*)d_in[8];

  char* ws = (char*)d_ws;
  constexpr size_t QB_OFF  = 0;                    // 2 MiB u16
  constexpr size_t KF_OFF  = (size_t)2  << 20;     // 2 MiB u16 (fragment-linear K)
  constexpr size_t VF_OFF  = (size_t)4  << 20;     // 4 MiB f32
  constexpr size_t VP_OFF  = (size_t)8  << 20;     // 2 MiB u16 (v' fragments)
  constexpr size_t ATT_OFF = (size_t)10 << 20;     // 8 MiB f32 (2 partials)
  constexpr size_t OUT_OFF = (size_t)18 << 20;     // 4 MiB f32
  constexpr size_t PT_OFF  = (size_t)22 << 20;     // 512 KiB f32

  u16*   qb   = (u16*)  (ws + QB_OFF);
  u16*   kfl  = (u16*)  (ws + KF_OFF);
  float* vf   = (float*)(ws + VF_OFF);
  u16*   vpb  = (u16*)  (ws + VP_OFF);
  float* attp = (float*)(ws + ATT_OFF);
  float* outp = (float*)(ws + OUT_OFF);
  float* part = (float*)(ws + PT_OFF);
  float* out  = (float*)d_out;

  hipLaunchKernelGGL(k_proj,    dim3(1024),       dim3(256), 0, stream,
                     x, Wq, bq, Wk, bk, Wv, bv, qb, kfl, vf);
  hipLaunchKernelGGL(k_csvp,    dim3(32, 16),     dim3(512), 0, stream,
                     qb, kfl, vf, vpb);
  hipLaunchKernelGGL(k_attn,    dim3(32, 2, 16),  dim3(256), 0, stream,
                     qb, kfl, vpb, attp);
  hipLaunchKernelGGL(k_oproj,   dim3(2048),       dim3(256), 0, stream,
                     attp, Wo, bo, outp, part);
  hipLaunchKernelGGL(k_softmax, dim3(64, 4),      dim3(256), 0, stream, outp, part, out);
}

// Round 7
// 173.778 us; speedup vs baseline: 1.0631x; 1.0333x over previous
//
#include <hip/hip_runtime.h>
#include <hip/hip_bf16.h>

// MultiHeadAttention B=4,S=4096,D=64,H=4,HD=16 on gfx950.
// softmax over QUERY axis => w[s,t] = E[s,t]/colsum[t], attended = E @ (V/colsum).
// Two MFMA passes recompute E (raw v_exp_f32).  Scores via 32x32x16 bf16 MFMA
// (K=16=HD exact).  PV consumes E directly as the B-operand; the implied k->t
// permutation is absorbed by pre-permuting v' in GLOBAL memory.
// R16: budget audit -- k_oproj had 64x redundant attp reads (each of 64
// threads re-loading the full 128-float att row: 524 MB of L3 traffic for a
// 16.8 MB array; attp doesn't fit per-XCD L2 and is written cross-XCD).
// Fix: LDS-stage the block's 8x128 att tile once (4 KB, one coalesced
// float4/thread), compute from LDS.  Summation order preserved -> bitwise
// identical.  Everything else unchanged from R15 (VMEM-free k_attn etc).

#define BB 4
#define SS 4096
#define DD 64
#define HH 4
#define HDD 16

typedef unsigned int u32;
typedef unsigned short u16;
typedef __attribute__((ext_vector_type(8))) short bfrag;     // 8 bf16
typedef __attribute__((ext_vector_type(4))) float floatx4;
typedef __attribute__((ext_vector_type(16))) float floatx16;
typedef __attribute__((ext_vector_type(2))) u32 u32x2;
typedef __attribute__((ext_vector_type(4))) u32 u32x4;

#define LOG2E 1.4426950408889634074f
#define QSCALE (LOG2E * 0.25f)

__device__ __forceinline__ float fexp2(float x) {   // raw v_exp_f32
#if __has_builtin(__builtin_amdgcn_exp2f)
  return __builtin_amdgcn_exp2f(x);
#else
  float r; asm("v_exp_f32 %0, %1" : "=v"(r) : "v"(x)); return r;
#endif
}
__device__ __forceinline__ float frcp(float x) {    // raw v_rcp_f32
#if __has_builtin(__builtin_amdgcn_rcpf)
  return __builtin_amdgcn_rcpf(x);
#else
  float r; asm("v_rcp_f32 %0, %1" : "=v"(r) : "v"(x)); return r;
#endif
}

__device__ __forceinline__ u16 f2bf(float f) {      // RNE
  u32 u = __builtin_bit_cast(u32, f);
  return (u16)((u + 0x7FFFu + ((u >> 16) & 1u)) >> 16);
}
// pack two fp32 -> bf16x2 by truncation (E>=0), single v_perm_b32
__device__ __forceinline__ u32 pack_bf(float lo, float hi) {
#if __has_builtin(__builtin_amdgcn_perm)
  return __builtin_amdgcn_perm(__builtin_bit_cast(u32, hi),
                               __builtin_bit_cast(u32, lo), 0x07060302u);
#else
  u32 a = __builtin_bit_cast(u32, lo);
  u32 b = __builtin_bit_cast(u32, hi);
  return (a >> 16) | (b & 0xFFFF0000u);
#endif
}

// global -> LDS DMA, 16B per lane.  LDS dest = wave-uniform base + lane*16.
__device__ __forceinline__ void gload_lds16(const u16* g, u16* l) {
  __builtin_amdgcn_global_load_lds(
      (const __attribute__((address_space(1))) void*)(g),
      (__attribute__((address_space(3))) void*)(l), 16, 0, 0);
}

// fragment column c (0..255 within a 256-t chunk) -> t within chunk.
__device__ __forceinline__ int tmap(int c) {
  int c5 = c & 31;
  return (c & ~31) + (c5 & 3) + ((c5 >> 2) & 1) * 8 + ((c5 >> 3) & 1) * 16
       + ((c5 >> 4) & 1) * 4;
}

// ---------------------------------------------------------------------------
// K1: projections. x[B,S,64] -> q bf16 (scaled, bias folded) [B,H,S,16];
// k bf16 FRAGMENT-LINEAR kfl[bh][t/32][lane=(e>>3)*32+(t&31)][j=e&7]
// (so K chunks DMA linearly into LDS and ds_read_b128 at lane*16B is
// conflict-free); v fp32 [B,H,S,16].
// ---------------------------------------------------------------------------
__global__ __launch_bounds__(256) void k_proj(
    const float* __restrict__ x,
    const float* __restrict__ Wq, const float* __restrict__ bq,
    const float* __restrict__ Wk, const float* __restrict__ bk,
    const float* __restrict__ Wv, const float* __restrict__ bv,
    u16* __restrict__ qb, u16* __restrict__ kfl, float* __restrict__ vf)
{
  __shared__ float xs[16 * 64];
  const int tid = threadIdx.x;
  const int blk = blockIdx.x;            // B*S/16 = 1024
  const int b   = blk >> 8;
  const int s0  = (blk & 255) << 4;
  ((float4*)xs)[tid] = ((const float4*)(x + ((size_t)b * SS + s0) * DD))[tid];
  __syncthreads();

  const int col = tid & 63, h = col >> 4, e = col & 15;
  const int rg  = tid >> 6;              // wave id; 4 rows each
  float aq[4] = {0,0,0,0}, ak[4] = {0,0,0,0}, av[4] = {0,0,0,0};
  const int wofs = h * (DD * HDD) + e;
#pragma unroll 4
  for (int d = 0; d < DD; ++d) {
    float wq = Wq[wofs + d * HDD];
    float wk = Wk[wofs + d * HDD];
    float wv = Wv[wofs + d * HDD];
    const float* xr = xs + (rg * 4) * 64 + d;
#pragma unroll
    for (int r = 0; r < 4; ++r) {
      float xv = xr[r * 64];
      aq[r] += xv * wq; ak[r] += xv * wk; av[r] += xv * wv;
    }
  }
  const float bqv = bq[col], bkv = bk[col], bvv = bv[col];
  const int bh = b * HH + h;
  size_t base = ((size_t)bh * SS + (s0 + rg * 4)) * HDD + e;
#pragma unroll
  for (int r = 0; r < 4; ++r) {
    int t = s0 + rg * 4 + r;
    qb[base + r * HDD] = f2bf((aq[r] + bqv) * QSCALE);
    vf[base + r * HDD] = av[r] + bvv;
    size_t kidx = (((size_t)bh * 128 + (t >> 5)) * 64
                 + (e >> 3) * 32 + (t & 31)) * 8 + (e & 7);
    kfl[kidx] = f2bf(ak[r] + bkv);
  }
}

// ---------------------------------------------------------------------------
// K2: fused colsum + v'-prep, 512-thr blocks.  Wave w: t-sub = w&3 (32 t),
// s-half = w>>2 (2048 s = 64 MFMAs).  mfma(Q,K): D[m=s][n=t], col=lane&31
// -> t; s-reduction IN-LANE + shfl_xor(32); two s-half partials combined in
// LDS.  Score-MFMA ping-pong with 4 rotating NAMED q regs.  kf reads the
// fragment-linear kfl (16B/lane contiguous).  Pack phase (threads 0..255)
// emits the swizzled/packed v' half-chunk: vp[bh][chunk256][flat4096],
// flat = e*256 + (cc^(e&7))*8 + j, c = cc*8+j, t = tmap(c).
// ---------------------------------------------------------------------------
__global__ __launch_bounds__(512, 4) void k_csvp(
    const u16* __restrict__ qb, const u16* __restrict__ kfl,
    const float* __restrict__ vf, u16* __restrict__ vp)
{
  __shared__ float vstage[128 * 16];     // [tl][e], 8 KB
  __shared__ float cpart[2][128];
  __shared__ float rcl[128];
  const int tid = threadIdx.x;
  const int lane = tid & 63, w = tid >> 6;
  const int l31 = lane & 31, hl = lane >> 5;
  const int bx = blockIdx.x;             // 32 t-blocks of 128
  const int bh = blockIdx.y;             // 16
  const int shalf = w >> 2;
  const size_t base = (size_t)bh * (SS * HDD);

  // stage the block's v tile (independent of the colsum stream)
  {
    const float4* vsrc4 = (const float4*)(vf + ((size_t)bh * SS + bx * 128) * HDD);
    ((float4*)vstage)[tid] = vsrc4[tid];
  }

  const int g = bx * 4 + (w & 3);
  const bfrag kf = *(const bfrag*)(kfl + (((size_t)bh * 128 + g) * 64 + lane) * 8);
  const u16* qpc = qb + base + ((size_t)shalf * 2048 + l31) * HDD + hl * 8;
  const floatx16 z16 = {0.f};
  float c0 = 0.f, c1 = 0.f, c2 = 0.f, c3 = 0.f;

#define LQ(i) (*(const bfrag*)(qpc + (size_t)(i) * (32 * HDD)))
#define ACCUM(dv)                                   \
  do {                                              \
    _Pragma("unroll")                               \
    for (int j = 0; j < 4; ++j) {                   \
      c0 += fexp2((dv)[4 * j + 0]);                 \
      c1 += fexp2((dv)[4 * j + 1]);                 \
      c2 += fexp2((dv)[4 * j + 2]);                 \
      c3 += fexp2((dv)[4 * j + 3]);                 \
    }                                               \
  } while (0)
#define STEP(qr, ri)                                                        \
  do {                                                                      \
    floatx16 dB = __builtin_amdgcn_mfma_f32_32x32x16_bf16(qr, kf, z16, 0, 0, 0); \
    qr = LQ(ri);                                                            \
    ACCUM(dA);                                                              \
    dA = dB;                                                                \
  } while (0)

  bfrag q0 = LQ(0), q1 = LQ(1), q2v = LQ(2), q3 = LQ(3);
  floatx16 dA = __builtin_amdgcn_mfma_f32_32x32x16_bf16(q0, kf, z16, 0, 0, 0);
  q0 = LQ(4);
#pragma unroll 1
  for (int o = 0; o < 2; ++o) {          // rolled: I-cache
#pragma unroll
    for (int i = 0; i < 32; i += 4) {
      STEP(q1,  i + 5);
      STEP(q2v, i + 6);
      STEP(q3,  i + 7);
      STEP(q0,  i + 8);
    }
    qpc += 32 * 32 * HDD;
  }
#undef STEP
#undef LQ
#undef ACCUM

  float c = (c0 + c1) + (c2 + c3);
  c += __shfl_xor(c, 32, 64);
  if (hl == 0)
    cpart[shalf][(w & 3) * 32 + l31] = c;
  __syncthreads();
  if (tid < 128)
    rcl[tid] = frcp(cpart[0][tid] + cpart[1][tid]);
  __syncthreads();

  // pack phase: threads 0..255 -> (e, poff); block owns half-chunk h0 = bx&1.
  if (tid < 256) {
    const int e = tid >> 4;                          // 0..15
    const int h0 = bx & 1;
    const int poff = h0 * 16 + (tid & 15);           // write cc-position
    const int cc = poff ^ (e & 7);                   // source column block
    const int h128 = h0 * 128;
    u32 r[4];
#pragma unroll
    for (int jj = 0; jj < 4; ++jj) {
      int ta = tmap(cc * 8 + 2 * jj)     - h128;     // local t within 128
      int tb = tmap(cc * 8 + 2 * jj + 1) - h128;
      u16 lo = f2bf(vstage[ta * 16 + e] * rcl[ta]);
      u16 hi = f2bf(vstage[tb * 16 + e] * rcl[tb]);
      r[jj] = (u32)lo | ((u32)hi << 16);
    }
    u16* outb = vp + ((size_t)bh * 16 + (bx >> 1)) * 4096;
    u32x4 vv = {r[0], r[1], r[2], r[3]};
    *(u32x4*)(outb + e * 256 + poff * 8) = vv;
  }
}

// ---------------------------------------------------------------------------
// K3: attended partials = E @ v' over a 2048-t half: eight 256-t chunks.
// Both K and v' chunks DMA into double-buffered LDS (global_load_lds) ->
// the inner loop is VMEM-FREE.  Per chunk: {vmcnt(0) [waits DMA issued a
// full chunk ago => ~free]; raw s_barrier; issue next chunk's DMA; 8 kf
// ds_read_b128 (conflict-free, lane*16B); 8 iters of score-MFMA ping-pong
// + 16 v_exp + 8 packs + 2 af ds_read + 2 PV MFMA into DUAL accumulators}.
// LDS 32.8 KB; grid 1024 = 4 blocks/CU exact; lb(256,4).
// ---------------------------------------------------------------------------
__global__ __launch_bounds__(256, 4) void k_attn(
    const u16* __restrict__ qb, const u16* __restrict__ kfl,
    const u16* __restrict__ vp, float* __restrict__ attp)
{
  __shared__ __align__(16) u16 vls[2][4096];       // 2 x 8 KB
  __shared__ __align__(16) u16 kls[2][4096];       // 2 x 8 KB
  const int tid  = threadIdx.x;
  const int lane = tid & 63, w = tid >> 6;
  const int l31 = lane & 31, hl = lane >> 5;
  const int bh = blockIdx.z, b = bh >> 2, h = bh & 3;
  const int tph = blockIdx.y;                      // 0..1 (t-half)
  const int s0 = blockIdx.x * 128 + w * 32;
  const size_t base = (size_t)bh * (SS * HDD);

  const bfrag qf = *(const bfrag*)(qb + base + (size_t)(s0 + l31) * HDD + hl * 8);
  const floatx16 z16 = {0.f};
  floatx16 acc0 = {0.f}, acc1 = {0.f};

  const u16* vsrc = vp  + ((size_t)bh * 16  + tph * 8)  * 4096;
  const u16* ksrc = kfl + ((size_t)bh * 128 + tph * 64) * 512;   // 8 grp/chunk

  // per-chunk DMA: wave w covers u16 [w*1024, w*1024+1024) of each 4096 buf
#define STAGE(ch, buf)                                                \
  do {                                                                \
    const u16* gv = vsrc + (ch) * 4096 + w * 1024 + lane * 8;         \
    u16* lv = &vls[buf][0] + w * 1024;                                \
    gload_lds16(gv, lv);                                              \
    gload_lds16(gv + 512, lv + 512);                                  \
    const u16* gk = ksrc + (ch) * 4096 + w * 1024 + lane * 8;         \
    u16* lk = &kls[buf][0] + w * 1024;                                \
    gload_lds16(gk, lk);                                              \
    gload_lds16(gk + 512, lk + 512);                                  \
  } while (0)

  STAGE(0, 0);

#pragma unroll
  for (int ch = 0; ch < 8; ++ch) {
    // my DMA for this chunk was issued a full chunk ago -> wait ~free;
    // barrier (no drain) publishes every wave's DMA and closes reads of
    // the buffer the next STAGE overwrites.
    asm volatile("s_waitcnt vmcnt(0)" ::: "memory");
    __builtin_amdgcn_s_barrier();
    __builtin_amdgcn_sched_barrier(0);
    if (ch < 7) STAGE(ch + 1, (ch + 1) & 1);

    const u16* vrow = &vls[ch & 1][0] + (l31 & 15) * 256;
    const u16* krow = &kls[ch & 1][0];
    const int eb = l31 & 7;

    bfrag kfr[4];                         // 4-slot rotation, static indices
#pragma unroll
    for (int it = 0; it < 4; ++it)
      kfr[it] = *(const bfrag*)(krow + it * 512 + lane * 8);
    floatx16 dA = __builtin_amdgcn_mfma_f32_32x32x16_bf16(kfr[0], qf, z16, 0, 0, 0);

#pragma unroll
    for (int it = 0; it < 8; ++it) {
      if (it < 4)                         // refill consumed slot with it+4
        kfr[it & 3] = *(const bfrag*)(krow + (it + 4) * 512 + lane * 8);
      floatx16 dB;
      if (it < 7)
        dB = __builtin_amdgcn_mfma_f32_32x32x16_bf16(kfr[(it + 1) & 3], qf, z16, 0, 0, 0);
      else
        dB = dA;
      // consume dA = score (ch, it)
      u32 wr[8];
#pragma unroll
      for (int p = 0; p < 8; ++p)
        wr[p] = pack_bf(fexp2(dA[2 * p]), fexp2(dA[2 * p + 1]));
      const int cc0 = it * 4 + hl * 2;
      u32x4 af0 = *(const u32x4*)(vrow + ((cc0 ^ eb) << 3));
      u32x4 af1 = *(const u32x4*)(vrow + (((cc0 + 1) ^ eb) << 3));
      u32x4 ef0 = {wr[0], wr[1], wr[2], wr[3]};
      u32x4 ef1 = {wr[4], wr[5], wr[6], wr[7]};
      acc0 = __builtin_amdgcn_mfma_f32_32x32x16_bf16(
          __builtin_bit_cast(bfrag, af0), __builtin_bit_cast(bfrag, ef0), acc0, 0, 0, 0);
      acc1 = __builtin_amdgcn_mfma_f32_32x32x16_bf16(
          __builtin_bit_cast(bfrag, af1), __builtin_bit_cast(bfrag, ef1), acc1, 0, 0, 0);
      dA = dB;
    }
  }
#undef STAGE

  floatx16 acc = acc0 + acc1;
  // D[e][s]: col=l31 -> s; rows r=0..3 -> e=4hl+r, r=4..7 -> e=8+4hl+(r-4)
  float* ao = attp + (((size_t)tph * BB + b) * SS + s0 + l31) * (HH * HDD)
            + h * HDD + 4 * hl;
  float4 lo4 = {acc[0], acc[1], acc[2], acc[3]};
  float4 hi4 = {acc[4], acc[5], acc[6], acc[7]};
  *(float4*)ao       = lo4;
  *(float4*)(ao + 8) = hi4;
}

// ---------------------------------------------------------------------------
// K4: out_pre = (sum of 2 attended partials) @ Wo + bo, fused partial expsum
// over each block's 8 rows -> part[b][512][64].  Wo AND the block's 8x128
// att tile staged in LDS (one coalesced float4/thread -> 64x less attp
// traffic than per-thread row reloads).  Same summation order as before.
// ---------------------------------------------------------------------------
__global__ __launch_bounds__(256) void k_oproj(
    const float* __restrict__ att, const float* __restrict__ Wo,
    const float* __restrict__ bo, float* __restrict__ outp,
    float* __restrict__ part)
{
  __shared__ float wols[64 * 64];
  __shared__ float atts[8][128];         // [row][half*64 + c]
  __shared__ float red[4][64];
  const int tid = threadIdx.x;
  const int blk = blockIdx.x;            // 2048
  const int b = blk >> 9, s0 = (blk & 511) << 3;
#pragma unroll
  for (int i = 0; i < 4; ++i)
    ((float4*)wols)[tid + 256 * i] = ((const float4*)Wo)[tid + 256 * i];
  // stage att tile: r = tid>>5, q = tid&31 -> half = q>>4, j4 = (q&15)*4
  {
    const int r = tid >> 5, q = tid & 31;
    const int half = q >> 4, j4 = (q & 15) << 2;
    const float4 v = *(const float4*)(
        att + (((size_t)half * BB + b) * SS + s0 + r) * 64 + j4);
    *(float4*)(&atts[r][half * 64 + j4]) = v;
  }
  __syncthreads();

  const int d = tid & 63, sg = tid >> 6;
  const float bov = bo[d];
  float es = 0.f;
#pragma unroll
  for (int r = 0; r < 2; ++r) {
    const int row = sg * 2 + r;
    float acc = bov;
#pragma unroll
    for (int c = 0; c < 64; ++c)
      acc += (atts[row][c] + atts[row][64 + c]) * wols[c * 64 + d];
    outp[((size_t)b * SS + s0 + row) * 64 + d] = acc;
    es += fexp2(acc * LOG2E);
  }
  red[sg][d] = es;
  __syncthreads();
  if (tid < 64)
    part[((size_t)b * 512 + (blk & 511)) * 64 + tid] =
        red[0][tid] + red[1][tid] + red[2][tid] + red[3][tid];
}

// ---------------------------------------------------------------------------
// K5: out = exp(out_pre) * rcp(sum_s exp(out_pre))  (512 partials per (b,d))
// ---------------------------------------------------------------------------
__global__ __launch_bounds__(256) void k_softmax(
    const float* __restrict__ outp, const float* __restrict__ part,
    float* __restrict__ out)
{
  __shared__ float red[4][64];
  __shared__ float rs[64];
  const int tid = threadIdx.x, d = tid & 63, sg = tid >> 6;
  const int st = blockIdx.x;             // 64 s-tiles of 64
  const int b = blockIdx.y;
  {
    float e = 0.f;
    const float* pp = part + ((size_t)b * 512 + sg * 128) * 64 + d;
#pragma unroll 8
    for (int c = 0; c < 128; ++c) e += pp[c * 64];
    red[sg][d] = e;
  }
  __syncthreads();
  if (tid < 64)
    rs[tid] = frcp(red[0][tid] + red[1][tid] + red[2][tid] + red[3][tid]);
  __syncthreads();
  const float r = rs[d];
  const size_t rowbase = ((size_t)b * SS + st * 64 + sg * 16) * 64 + d;
#pragma unroll 4
  for (int i = 0; i < 16; ++i)
    out[rowbase + i * 64] = fexp2(outp[rowbase + i * 64] * LOG2E) * r;
}

// ---------------------------------------------------------------------------
extern "C" void kernel_launch(void* const* d_in, const int* in_sizes, int n_in,
                              void* d_out, int out_size, void* d_ws, size_t ws_size,
                              hipStream_t stream) {
  const float* x  = (const float*)d_in[0];
  const float* Wq = (const float*)d_in[1];
  const float* bq = (const float*)d_in[2];
  const float* Wk = (const float*)d_in[3];
  const float* bk = (const float*)d_in[4];
  const float* Wv = (const float*)d_in[5];
  const float* bv = (const float*)d_in[6];
  const float* Wo = (const float*)d_in[7];
  const float* bo = (const float*)d_in[8];

  char* ws = (char*)d_ws;
  constexpr size_t QB_OFF  = 0;                    // 2 MiB u16
  constexpr size_t KF_OFF  = (size_t)2  << 20;     // 2 MiB u16 (fragment-linear K)
  constexpr size_t VF_OFF  = (size_t)4  << 20;     // 4 MiB f32
  constexpr size_t VP_OFF  = (size_t)8  << 20;     // 2 MiB u16 (v' fragments)
  constexpr size_t ATT_OFF = (size_t)10 << 20;     // 8 MiB f32 (2 partials)
  constexpr size_t OUT_OFF = (size_t)18 << 20;     // 4 MiB f32
  constexpr size_t PT_OFF  = (size_t)22 << 20;     // 512 KiB f32

  u16*   qb   = (u16*)  (ws + QB_OFF);
  u16*   kfl  = (u16*)  (ws + KF_OFF);
  float* vf   = (float*)(ws + VF_OFF);
  u16*   vpb  = (u16*)  (ws + VP_OFF);
  float* attp = (float*)(ws + ATT_OFF);
  float* outp = (float*)(ws + OUT_OFF);
  float* part = (float*)(ws + PT_OFF);
  float* out  = (float*)d_out;

  hipLaunchKernelGGL(k_proj,    dim3(1024),       dim3(256), 0, stream,
                     x, Wq, bq, Wk, bk, Wv, bv, qb, kfl, vf);
  hipLaunchKernelGGL(k_csvp,    dim3(32, 16),     dim3(512), 0, stream,
                     qb, kfl, vf, vpb);
  hipLaunchKernelGGL(k_attn,    dim3(32, 2, 16),  dim3(256), 0, stream,
                     qb, kfl, vpb, attp);
  hipLaunchKernelGGL(k_oproj,   dim3(2048),       dim3(256), 0, stream,
                     attp, Wo, bo, outp, part);
  hipLaunchKernelGGL(k_softmax, dim3(64, 4),      dim3(256), 0, stream, outp, part, out);
}